// Round 3
// baseline (1739.844 us; speedup 1.0000x reference)
//
#include <hip/hip_runtime.h>
#include <hip/hip_bf16.h>
#include <math.h>
#include <stdint.h>

#define PI_F 3.14159265358979323846f

typedef __hip_bfloat16 bf16;
typedef __attribute__((ext_vector_type(8))) short short8;   // 8 x bf16 (4 VGPRs)
typedef __attribute__((ext_vector_type(4))) float floatx4;

static constexpr int DIM = 4096;

// ---------- helpers ----------
__device__ __forceinline__ unsigned short f2bf_bits(float f) {
    __hip_bfloat16 h = __float2bfloat16(f);
    return __builtin_bit_cast(unsigned short, h);
}
__device__ __forceinline__ float bf2f_bits(unsigned short u) {
    return __builtin_bit_cast(float, ((unsigned int)u) << 16);
}
// async global->LDS, 16B per lane; LDS dest is wave-uniform base (+lane*16 implicit)
__device__ __forceinline__ void load_lds16(const void* gsrc, void* lds) {
    __builtin_amdgcn_global_load_lds(
        (__attribute__((address_space(1))) void*)gsrc,
        (__attribute__((address_space(3))) void*)lds,
        16, 0, 0);
}

// ---------- cast fp32 -> bf16, 4 elems/thread ----------
__global__ __launch_bounds__(256)
void cast_f32_bf16(const float* __restrict__ src, unsigned short* __restrict__ dst, int n4) {
    int i = blockIdx.x * 256 + threadIdx.x;
    if (i < n4) {
        float4 v = ((const float4*)src)[i];
        ushort4 o;
        o.x = f2bf_bits(v.x); o.y = f2bf_bits(v.y);
        o.z = f2bf_bits(v.z); o.w = f2bf_bits(v.w);
        ((ushort4*)dst)[i] = o;
    }
}

// ---------- pack Wk,Wq into Wt[k][p] fp32 (p<64: Wk, p>=64: Wq) ----------
__global__ __launch_bounds__(256)
void transpose_wkq(const float* __restrict__ Wk, const float* __restrict__ Wq,
                   float* __restrict__ Wt) {
    int idx = blockIdx.x * 256 + threadIdx.x;   // over 4096*128
    int k = idx >> 7, p = idx & 127;
    float v = (p < 64) ? Wk[(size_t)p * DIM + k] : Wq[(size_t)(p - 64) * DIM + k];
    Wt[idx] = v;
}

// ---------- fused phase GEMM (fp32, exact) + tanh/cos/softplus -> scale[row] ----------
// block: 256 thr = 8 row-groups x 32 col-groups; 32 rows x 128 cols per block; grid 256
__global__ __launch_bounds__(256)
void phase_kernel(const float* __restrict__ x, const float* __restrict__ Wt,
                  const float* __restrict__ bk, const float* __restrict__ bq,
                  float* __restrict__ scale)
{
    const int tid = threadIdx.x;
    const int rg  = tid >> 5;          // 0..7 -> rows rg*4..+4
    const int cg  = tid & 31;          // 0..31 -> cols cg*4..+4
    const size_t row0 = (size_t)blockIdx.x * 32;

    float acc[4][4] = {};
    const float* xp = x + (row0 + (size_t)rg * 4) * DIM;

    for (int k = 0; k < DIM; k += 4) {
        const float4 w0 = *(const float4*)(Wt + (size_t)(k + 0) * 128 + cg * 4);
        const float4 w1 = *(const float4*)(Wt + (size_t)(k + 1) * 128 + cg * 4);
        const float4 w2 = *(const float4*)(Wt + (size_t)(k + 2) * 128 + cg * 4);
        const float4 w3 = *(const float4*)(Wt + (size_t)(k + 3) * 128 + cg * 4);
        #pragma unroll
        for (int r = 0; r < 4; ++r) {
            const float4 xv = *(const float4*)(xp + (size_t)r * DIM + k);
            acc[r][0] += xv.x * w0.x + xv.y * w1.x + xv.z * w2.x + xv.w * w3.x;
            acc[r][1] += xv.x * w0.y + xv.y * w1.y + xv.z * w2.y + xv.w * w3.y;
            acc[r][2] += xv.x * w0.z + xv.y * w1.z + xv.z * w2.z + xv.w * w3.z;
            acc[r][3] += xv.x * w0.w + xv.y * w1.w + xv.z * w2.w + xv.w * w3.w;
        }
    }

    __shared__ float ph[32][128];
    #pragma unroll
    for (int r = 0; r < 4; ++r) {
        #pragma unroll
        for (int c = 0; c < 4; ++c) {
            const int col = cg * 4 + c;
            const float b = (col < 64) ? bk[col] : bq[col - 64];
            ph[rg * 4 + r][col] = PI_F * tanhf(acc[r][c] + b);
        }
    }
    __syncthreads();
    const int rr = tid >> 3;           // 0..31 row
    const int jj = tid & 7;            // 0..7 p-chunk
    float part = 0.f;
    #pragma unroll
    for (int p = 0; p < 8; ++p) {
        const int pp = jj * 8 + p;
        part += cosf(ph[rr][pp] - ph[rr][64 + pp]);
    }
    __shared__ float ps[32][8];
    ps[rr][jj] = part;
    __syncthreads();
    if (tid < 32) {
        float a = 0.f;
        #pragma unroll
        for (int j = 0; j < 8; ++j) a += ps[tid][j];
        const float gsp = log1pf(expf(a * (1.f / 64.f) + 0.5f));   // softplus
        scale[row0 + tid] = a * gsp * (1.f / 64.f);
    }
}

// ---------- m97-style bf16 MFMA GEMM: C[m][n] = sum_k A[m][k]*Bm[n][k] (+epilogue) ----------
// MODE 1: nbuf = bf16( (dot + bias[n]) * scale[m] )            (V path, bf16 out)
// MODE 2: out  = fp32( dot + bias[n] + xres[m][n] )            (output path, fp32 out)
template <int MODE>
__global__ __launch_bounds__(256)
void gemm_bt(const bf16* __restrict__ A, const bf16* __restrict__ Bm,
             const float* __restrict__ bias, const float* __restrict__ scale,
             const float* __restrict__ xres, bf16* __restrict__ outBf,
             float* __restrict__ outF, int N)
{
    constexpr int K = 4096;
    __shared__ __align__(16) bf16 As[128 * 32];
    __shared__ __align__(16) bf16 Bs[128 * 32];
    const int tid  = threadIdx.x;
    const int lane = tid & 63;
    const int wave = tid >> 6;
    const size_t bm = (size_t)blockIdx.x * 128;
    const size_t bn = (size_t)blockIdx.y * 128;
    const int wr  = (wave >> 1) * 64;
    const int wc  = (wave & 1) * 64;
    const int q   = lane >> 4;
    const int m16 = lane & 15;

    floatx4 acc[4][4] = {};

    // staging: chunk c (16B = 8 bf16) -> tile row c>>2, k-col (c&3)*8; thread does chunks tid, tid+256
    const int r0 = tid >> 2,         col0 = (tid & 3) << 3;
    const int r1 = (tid + 256) >> 2, col1 = (tid & 3) << 3;
    bf16* lA0 = As + (size_t)(wave * 64) * 8;          // wave-uniform LDS bases
    bf16* lA1 = As + (size_t)(256 + wave * 64) * 8;
    bf16* lB0 = Bs + (size_t)(wave * 64) * 8;
    bf16* lB1 = Bs + (size_t)(256 + wave * 64) * 8;
    const bf16* gA0 = A  + (bm + r0) * K + col0;
    const bf16* gA1 = A  + (bm + r1) * K + col1;
    const bf16* gB0 = Bm + (bn + r0) * K + col0;
    const bf16* gB1 = Bm + (bn + r1) * K + col1;

    for (int k0 = 0; k0 < K; k0 += 32) {
        load_lds16(gA0 + k0, lA0);
        load_lds16(gA1 + k0, lA1);
        load_lds16(gB0 + k0, lB0);
        load_lds16(gB1 + k0, lB1);
        __syncthreads();
        short8 af[4], bfv[4];
        #pragma unroll
        for (int i = 0; i < 4; ++i)
            af[i] = *(const short8*)(As + (size_t)(wr + i * 16 + m16) * 32 + q * 8);
        #pragma unroll
        for (int j = 0; j < 4; ++j)
            bfv[j] = *(const short8*)(Bs + (size_t)(wc + j * 16 + m16) * 32 + q * 8);
        #pragma unroll
        for (int i = 0; i < 4; ++i) {
            #pragma unroll
            for (int j = 0; j < 4; ++j)
                acc[i][j] = __builtin_amdgcn_mfma_f32_16x16x32_bf16(af[i], bfv[j], acc[i][j], 0, 0, 0);
        }
        __syncthreads();
    }

    // epilogue: C/D layout col=lane&15, row=(lane>>4)*4+reg
    #pragma unroll
    for (int i = 0; i < 4; ++i) {
        #pragma unroll
        for (int j = 0; j < 4; ++j) {
            const size_t col = bn + wc + j * 16 + m16;
            const float bv = bias[col];
            #pragma unroll
            for (int r = 0; r < 4; ++r) {
                const size_t row = bm + wr + i * 16 + q * 4 + r;
                float v = acc[i][j][r] + bv;
                if (MODE == 1) {
                    v *= scale[row];
                    outBf[row * (size_t)N + col] = __float2bfloat16(v);
                } else {
                    v += xres[row * (size_t)DIM + col];
                    outF[row * (size_t)N + col] = v;    // fp32 output
                }
            }
        }
    }
}

// ---------- in-place LayerNorm over each row of bf16 buffer ----------
__global__ __launch_bounds__(256)
void ln_kernel(bf16* __restrict__ o, const float* __restrict__ g, const float* __restrict__ b)
{
    const size_t row = blockIdx.x;
    unsigned short* p = (unsigned short*)(o + row * DIM);
    const int tid = threadIdx.x;
    float s = 0.f, s2 = 0.f;
    float vals[16];
    #pragma unroll
    for (int c = 0; c < 4; ++c) {
        ushort4 u = ((const ushort4*)p)[tid + c * 256];
        float v0 = bf2f_bits(u.x), v1 = bf2f_bits(u.y);
        float v2 = bf2f_bits(u.z), v3 = bf2f_bits(u.w);
        vals[c * 4 + 0] = v0; vals[c * 4 + 1] = v1;
        vals[c * 4 + 2] = v2; vals[c * 4 + 3] = v3;
        s  += v0 + v1 + v2 + v3;
        s2 += v0 * v0 + v1 * v1 + v2 * v2 + v3 * v3;
    }
    #pragma unroll
    for (int off = 32; off; off >>= 1) {
        s  += __shfl_down(s, off, 64);
        s2 += __shfl_down(s2, off, 64);
    }
    __shared__ float red[2][4];
    const int wv = tid >> 6, ln = tid & 63;
    if (ln == 0) { red[0][wv] = s; red[1][wv] = s2; }
    __syncthreads();
    const float ts  = red[0][0] + red[0][1] + red[0][2] + red[0][3];
    const float ts2 = red[1][0] + red[1][1] + red[1][2] + red[1][3];
    const float mean = ts * (1.f / 4096.f);
    const float var  = ts2 * (1.f / 4096.f) - mean * mean;
    const float rstd = rsqrtf(var + 1e-5f);
    #pragma unroll
    for (int c = 0; c < 4; ++c) {
        const int idx = (tid + c * 256) * 4;
        ushort4 u;
        u.x = f2bf_bits((vals[c * 4 + 0] - mean) * rstd * g[idx + 0] + b[idx + 0]);
        u.y = f2bf_bits((vals[c * 4 + 1] - mean) * rstd * g[idx + 1] + b[idx + 1]);
        u.z = f2bf_bits((vals[c * 4 + 2] - mean) * rstd * g[idx + 2] + b[idx + 2]);
        u.w = f2bf_bits((vals[c * 4 + 3] - mean) * rstd * g[idx + 3] + b[idx + 3]);
        ((ushort4*)p)[tid + c * 256] = u;
    }
}

extern "C" void kernel_launch(void* const* d_in, const int* in_sizes, int n_in,
                              void* d_out, int out_size, void* d_ws, size_t ws_size,
                              hipStream_t stream)
{
    // Inputs are fp32 per the reference contract (round-2 NaN proved they are
    // not bf16). Output is fp32 (round-1's 10.7 absmax matched the
    // bf16-written/fp32-read + half-unwritten-buffer signature).
    const float* x   = (const float*)d_in[0];
    const float* Wk  = (const float*)d_in[1];
    const float* bk  = (const float*)d_in[2];
    const float* Wq  = (const float*)d_in[3];
    const float* bq  = (const float*)d_in[4];
    const float* Wv  = (const float*)d_in[5];
    const float* bv  = (const float*)d_in[6];
    const float* lng = (const float*)d_in[7];
    const float* lnb = (const float*)d_in[8];
    const float* Wo  = (const float*)d_in[9];
    const float* bo  = (const float*)d_in[10];

    char* ws = (char*)d_ws;
    bf16*  x_bf  = (bf16*)(ws);                       //  64 MiB  [8192][4096]
    bf16*  Wv_bf = (bf16*)(ws + 67108864);            //  32 MiB  [4096][4096]
    bf16*  Wo_bf = (bf16*)(ws + 100663296);           //  32 MiB  [4096][4096]
    float* Wt    = (float*)(ws + 134217728);          //   2 MiB  [4096][128]
    float* scl   = (float*)(ws + 136314880);          //  32 KiB  [8192]
    bf16*  nbuf  = (bf16*)(ws + 136347648);           //  64 MiB  [8192][4096]
    // total ws use: ~194 MiB

    cast_f32_bf16<<<8388608 / 256, 256, 0, stream>>>(x,  (unsigned short*)x_bf,  8388608);
    cast_f32_bf16<<<4194304 / 256, 256, 0, stream>>>(Wv, (unsigned short*)Wv_bf, 4194304);
    cast_f32_bf16<<<4194304 / 256, 256, 0, stream>>>(Wo, (unsigned short*)Wo_bf, 4194304);
    transpose_wkq<<<2048, 256, 0, stream>>>(Wk, Wq, Wt);
    phase_kernel<<<256, 256, 0, stream>>>(x, Wt, bk, bq, scl);
    // V = (x @ Wv^T + bv) * scale  -> nbuf (bf16)
    gemm_bt<1><<<dim3(64, 32), 256, 0, stream>>>(x_bf, Wv_bf, bv, scl, nullptr,
                                                 nbuf, nullptr, DIM);
    // LayerNorm in place
    ln_kernel<<<8192, 256, 0, stream>>>(nbuf, lng, lnb);
    // out = x + normed @ Wo^T + bo  (fp32 out)
    gemm_bt<2><<<dim3(64, 32), 256, 0, stream>>>(nbuf, Wo_bf, bo, nullptr, x,
                                                 nullptr, (float*)d_out, DIM);
}